// Round 17
// baseline (96.245 us; speedup 1.0000x reference)
//
#include <hip/hip_runtime.h>

// Problem constants (from reference)
constexpr int L  = 250;   // layers
constexpr int T  = 600;   // traces
constexpr int A  = 30;    // angles

typedef _Float16 h8    __attribute__((ext_vector_type(8)));  // MFMA A/B frag (4 VGPR)
typedef __fp16   f16x2 __attribute__((ext_vector_type(2)));  // cvt_pkrtz result type
typedef float    f4    __attribute__((ext_vector_type(4)));  // MFMA C/D frag
// 8-B-aligned float4 (odd wm rows are 1000 B apart); dwordx4 needs 4-B HW align
typedef float    f4u   __attribute__((ext_vector_type(4), aligned(8)));

// refT LDS row stride (halfs): 264 = 256+8 -> 16-B aligned rows, 2-way-free banks
constexpr int RT_LD = 264;

// ---------------- R31: R29 with the cvt_pkrtz TYPE fixed ---------------------
// R30 failed to COMPILE: __builtin_amdgcn_cvt_pkrtz returns
// __fp16 ext_vector_type(2), my union used _Float16 pairs (incompatible
// element types, though layout-identical). Fix: union pairs are f16x2
// (__fp16); the h8 view feeding the MFMA is unchanged. Zero semantic delta
// from R29's design; predictions carry over (vs R28 = 95.2 us harness):
//   PASS, absmax 0.004-0.010; harness 91-94 us; VALUBusy -2-4 pts.
//   If flat or absmax degrades -> revert R28, declare roofline.
//
// R29 delta over R28 (closed-form Rpp, 99.5 -> 95.2 us proven): phase-2 wm
// fragment conversion via v_cvt_pkrtz_f16_f32 (1 instr -> packed 2xf16, no
// pack move): 4 instr/fragment vs ~12, ~250 VALU ops/thread saved. RTZ on
// the wm A-operand only (<=1 ulp f16/element); refT path untouched. All
// else R28 byte-identical (proven family: registers + scattered wm + refT
// write-once + read-only K-loop + plain stores + 256 thr + grid 600).
// NO workspace, NO producer, NO in-loop ds_writes.
__global__ __launch_bounds__(256)
void zoep_fused(const float* __restrict__ vp,
                const float* __restrict__ vs,
                const float* __restrict__ rho,
                const float* __restrict__ theta,
                const float* __restrict__ wm,
                float* __restrict__ out)
{
    __shared__ _Float16 refT[32 * RT_LD];   // 16.5 KB: refT[a][k]
    __shared__ float sth_s[32];
    __shared__ float cth_s[32];

    const int tid = threadIdx.x;
    const int t   = blockIdx.x;

    if (tid < 32) {
        const float th = (tid < A) ? theta[tid] : 0.0f;
        sth_s[tid] = sinf(th);
        cth_s[tid] = cosf(th);
    }
    __syncthreads();

    // ---- Phase 1: closed-form Zoeppritz Rpp (R28-proven) --------------------
    const int  k     = tid;
    const bool valid = (k < L - 1);
    const int  kc    = valid ? k : (L - 2);   // clamped: loads always in-bounds

    const float a1 = vp[kc * T + t];          // lane-distinct lines, 1 instr/array
    const float a2 = vp[(kc + 1) * T + t];
    const float b1 = vs[kc * T + t];
    const float b2 = vs[(kc + 1) * T + t];
    const float r1 = rho[kc * T + t];
    const float r2 = rho[(kc + 1) * T + t];

    // Per-k hoists
    const float ra1  = __builtin_amdgcn_rcpf(a1);
    const float ra2  = __builtin_amdgcn_rcpf(a2);
    const float rb1i = __builtin_amdgcn_rcpf(b1);
    const float rb2i = __builtin_amdgcn_rcpf(b2);
    const float b1sq = b1 * b1;
    const float b2sq = b2 * b2;
    const float a2sq = a2 * a2;
    const float dd   = 2.0f * (r2 * b2sq - r1 * b1sq);

#pragma unroll 5
    for (int a = 0; a < A; ++a) {
        const float sth = sth_s[a];           // LDS broadcast (uniform a)
        const float cth = cth_s[a];

        const float p   = sth * ra1;          // ray parameter
        const float p2  = p * p;
        const float x1  = b1sq * p2;          // sin^2 phi1
        const float x2  = b2sq * p2;          // sin^2 phi2
        const float t2  = a2sq * p2;          // sin^2 theta2 (<= 0.71, ranges)
        const float c2  = sqrtf(1.0f - t2);   // cos theta2
        const float cp1 = sqrtf(1.0f - x1);   // cos phi1
        const float cp2 = sqrtf(1.0f - x2);   // cos phi2

        const float m1 = r1 * (1.0f - 2.0f * x1);
        const float m2 = r2 * (1.0f - 2.0f * x2);
        const float av = m2 - m1;
        const float bv = m2 + 2.0f * (r1 * x1);
        const float cv = m1 + 2.0f * (r2 * x2);

        const float C1 = cth * ra1;
        const float C2 = c2  * ra2;
        const float C3 = cp1 * rb1i;
        const float C4 = cp2 * rb2i;

        const float bC1 = bv * C1, cC2 = cv * C2;
        const float bC3 = bv * C3, cC4 = cv * C4;
        const float E   = bC1 + cC2;
        const float F   = bC3 + cC4;
        const float d14 = dd * C1 * C4;
        const float d23 = dd * C2 * C3;
        const float G   = av - d14;
        const float H   = av - d23;
        const float Hp2 = H * p2;
        const float D   = E * F + G * Hp2;
        const float N   = F * (bC1 - cC2) - Hp2 * (av + d14);
        const float res = N * __builtin_amdgcn_rcpf(D);

        refT[a * RT_LD + k] = (_Float16)(valid ? res : 0.0f);
    }
    // zero pad rows a = 30, 31 (column k)
    refT[30 * RT_LD + k] = (_Float16)0.0f;
    refT[31 * RT_LD + k] = (_Float16)0.0f;
    __syncthreads();

    // ---- Phase 2: MFMA GEMM (R22 chassis; pkrtz fragment conversion) --------
    // Verified layouts (R12): A[m=lane&15][k=quad*8+j], B[k=quad*8+j][n=lane&15],
    // C/D[row=quad*4+reg][col=lane&15].
    const int w    = tid >> 6;       // wave 0..3
    const int lane = tid & 63;
    const int quad = lane >> 4;      // 0..3
    const int n16  = lane & 15;

    f4 acc[4][2];
#pragma unroll
    for (int mi = 0; mi < 4; ++mi)
#pragma unroll
        for (int nt = 0; nt < 2; ++nt) acc[mi][nt] = (f4){0.f, 0.f, 0.f, 0.f};

    // Hoisted, clamped wm row pointers (R15-proven; store-masked at epilogue)
    const float* wrow[4];
#pragma unroll
    for (int mi = 0; mi < 4; ++mi) {
        const int m = (w * 4 + mi) * 16 + n16;        // logical wm row 0..255
        wrow[mi] = wm + ((m < L) ? m : (L - 1)) * L;
    }

    union PK { f16x2 p[4]; h8 v; };  // static-indexed pair assembly (reg-only)

    // ks = 0..6: cols kofs..kofs+7 <= 223 < 250 -> no clamps; 2x dwordx4 +
    // 4x v_cvt_pkrtz_f16_f32 per fragment (was 8 cvt + pack moves).
#pragma unroll
    for (int ks = 0; ks < 7; ++ks) {
        const int kofs = ks * 32 + quad * 8;
        const h8 b0  = *(const h8*)&refT[ n16       * RT_LD + kofs];
        const h8 b1v = *(const h8*)&refT[(16 + n16) * RT_LD + kofs];
#pragma unroll
        for (int mi = 0; mi < 4; ++mi) {
            const f4u g0 = *(const f4u*)(wrow[mi] + kofs);
            const f4u g1 = *(const f4u*)(wrow[mi] + kofs + 4);
            PK u;
            u.p[0] = __builtin_amdgcn_cvt_pkrtz(g0[0], g0[1]);
            u.p[1] = __builtin_amdgcn_cvt_pkrtz(g0[2], g0[3]);
            u.p[2] = __builtin_amdgcn_cvt_pkrtz(g1[0], g1[1]);
            u.p[3] = __builtin_amdgcn_cvt_pkrtz(g1[2], g1[3]);
            acc[mi][0] = __builtin_amdgcn_mfma_f32_16x16x32_f16(u.v, b0,  acc[mi][0], 0, 0, 0);
            acc[mi][1] = __builtin_amdgcn_mfma_f32_16x16x32_f16(u.v, b1v, acc[mi][1], 0, 0, 0);
        }
    }
    { // ks = 7: cols 224..255 - only quad==3 (248..255) partial. R12 boundary
      // semantics (pair-clamp + zero-select) with pkrtz after the selects.
        const int kofs = 224 + quad * 8;
        const h8 b0  = *(const h8*)&refT[ n16       * RT_LD + kofs];
        const h8 b1v = *(const h8*)&refT[(16 + n16) * RT_LD + kofs];
#pragma unroll
        for (int mi = 0; mi < 4; ++mi) {
            PK u;
#pragma unroll
            for (int c = 0; c < 4; ++c) {
                const int col  = kofs + 2 * c;                    // even
                const int colc = (col <= L - 2) ? col : (L - 2);  // pair start <= 248
                const float2 f = *(const float2*)(wrow[mi] + colc); // 8-B aligned
                const float fx = (col     < L) ? f.x : 0.0f;
                const float fy = (col + 1 < L) ? f.y : 0.0f;
                u.p[c] = __builtin_amdgcn_cvt_pkrtz(fx, fy);
            }
            acc[mi][0] = __builtin_amdgcn_mfma_f32_16x16x32_f16(u.v, b0,  acc[mi][0], 0, 0, 0);
            acc[mi][1] = __builtin_amdgcn_mfma_f32_16x16x32_f16(u.v, b1v, acc[mi][1], 0, 0, 0);
        }
    }

    // ---- Epilogue: D[row=quad*4+r][col=n16] -> out[t][l][a] ---- (R12 verbatim)
    float* outt = out + (size_t)t * (L * A);
#pragma unroll
    for (int mi = 0; mi < 4; ++mi) {
        const int mbase = (w * 4 + mi) * 16 + quad * 4;
#pragma unroll
        for (int nt = 0; nt < 2; ++nt) {
            const int a = nt * 16 + n16;
            if (a < A) {
#pragma unroll
                for (int r = 0; r < 4; ++r) {
                    const int l = mbase + r;
                    if (l < L) outt[l * A + a] = acc[mi][nt][r];
                }
            }
        }
    }
}

extern "C" void kernel_launch(void* const* d_in, const int* in_sizes, int n_in,
                              void* d_out, int out_size, void* d_ws, size_t ws_size,
                              hipStream_t stream) {
    (void)in_sizes; (void)n_in; (void)out_size; (void)d_ws; (void)ws_size;
    const float* vp    = (const float*)d_in[0];
    const float* vs    = (const float*)d_in[1];
    const float* rho   = (const float*)d_in[2];
    const float* theta = (const float*)d_in[3];
    const float* wm    = (const float*)d_in[4];
    float* out = (float*)d_out;

    zoep_fused<<<dim3(T), dim3(256), 0, stream>>>(vp, vs, rho, theta, wm, out);
}

// Round 18
// 95.393 us; speedup vs baseline: 1.0089x; 1.0089x over previous
//
#include <hip/hip_runtime.h>

// Problem constants (from reference)
constexpr int L  = 250;   // layers
constexpr int T  = 600;   // traces
constexpr int A  = 30;    // angles

typedef _Float16 h8  __attribute__((ext_vector_type(8)));   // MFMA A/B frag (4 VGPR)
typedef float    f4  __attribute__((ext_vector_type(4)));   // MFMA C/D frag
// 8-B-aligned float4 (odd wm rows are 1000 B apart); dwordx4 needs 4-B HW align
typedef float    f4u __attribute__((ext_vector_type(4), aligned(8)));

// refT LDS row stride (halfs): 264 = 256+8 -> 16-B aligned rows, 2-way-free banks
constexpr int RT_LD = 264;

// ---------------- R32: FINAL — R28 re-anchored (session best, 95.2 us) -------
// R31 (pkrtz packed conversion) was FLAT (96.25 vs 95.17): phase-2 cvt ops
// were already latency-hidden -> K-loop is load-latency-structural, not
// VALU-count-bound. Per pre-commitment, revert to R28 (best proven, RNE
// numerics) and declare the floor.
//
// What this kernel is: the R12/R22 proven chassis (registers + scattered wm
// loads + refT write-once-before-one-barrier + read-only K-loop + plain
// stores + 256 thr + grid 600) with phase-1 replaced by the closed-form
// Zoeppritz Rpp (Aki-Richards/Dvorkin exact form; R28, -4.3 us, the
// session's one algorithmic win).
//
// Closed structure space (R13-R26 ledger):
//   correctness: in-loop/reused LDS staging (5 sync disciplines), producer
//     kernel + d_ws, atomicAdd combine, 512 threads;
//   performance: angle/M/K splits (write-amp or phase-1 tax), monolithic
//     stage (LDS->1blk/CU), register prefetch (VGPR collapse);
//   flat: load width (R22), phase-1 unroll (R27), pkrtz (R31).
// Floor arithmetic: ~1140 VALU + 90 trans per thread (phase 1) + 256
// scattered 64-line A-loads per wave (phase 2) at the structure-pinned
// ~40% issue efficiency ~= 37 us kernel / ~95 us harness.
__global__ __launch_bounds__(256)
void zoep_fused(const float* __restrict__ vp,
                const float* __restrict__ vs,
                const float* __restrict__ rho,
                const float* __restrict__ theta,
                const float* __restrict__ wm,
                float* __restrict__ out)
{
    __shared__ _Float16 refT[32 * RT_LD];   // 16.5 KB: refT[a][k]
    __shared__ float sth_s[32];
    __shared__ float cth_s[32];

    const int tid = threadIdx.x;
    const int t   = blockIdx.x;

    if (tid < 32) {
        const float th = (tid < A) ? theta[tid] : 0.0f;
        sth_s[tid] = sinf(th);
        cth_s[tid] = cosf(th);
    }
    __syncthreads();

    // ---- Phase 1: closed-form Zoeppritz Rpp (R28-proven) --------------------
    const int  k     = tid;
    const bool valid = (k < L - 1);
    const int  kc    = valid ? k : (L - 2);   // clamped: loads always in-bounds

    const float a1 = vp[kc * T + t];          // lane-distinct lines, 1 instr/array
    const float a2 = vp[(kc + 1) * T + t];
    const float b1 = vs[kc * T + t];
    const float b2 = vs[(kc + 1) * T + t];
    const float r1 = rho[kc * T + t];
    const float r2 = rho[(kc + 1) * T + t];

    // Per-k hoists
    const float ra1  = __builtin_amdgcn_rcpf(a1);
    const float ra2  = __builtin_amdgcn_rcpf(a2);
    const float rb1i = __builtin_amdgcn_rcpf(b1);
    const float rb2i = __builtin_amdgcn_rcpf(b2);
    const float b1sq = b1 * b1;
    const float b2sq = b2 * b2;
    const float a2sq = a2 * a2;
    const float dd   = 2.0f * (r2 * b2sq - r1 * b1sq);

#pragma unroll 5
    for (int a = 0; a < A; ++a) {
        const float sth = sth_s[a];           // LDS broadcast (uniform a)
        const float cth = cth_s[a];

        const float p   = sth * ra1;          // ray parameter
        const float p2  = p * p;
        const float x1  = b1sq * p2;          // sin^2 phi1
        const float x2  = b2sq * p2;          // sin^2 phi2
        const float t2  = a2sq * p2;          // sin^2 theta2 (<= 0.71, ranges)
        const float c2  = sqrtf(1.0f - t2);   // cos theta2
        const float cp1 = sqrtf(1.0f - x1);   // cos phi1
        const float cp2 = sqrtf(1.0f - x2);   // cos phi2

        const float m1 = r1 * (1.0f - 2.0f * x1);
        const float m2 = r2 * (1.0f - 2.0f * x2);
        const float av = m2 - m1;
        const float bv = m2 + 2.0f * (r1 * x1);
        const float cv = m1 + 2.0f * (r2 * x2);

        const float C1 = cth * ra1;
        const float C2 = c2  * ra2;
        const float C3 = cp1 * rb1i;
        const float C4 = cp2 * rb2i;

        const float bC1 = bv * C1, cC2 = cv * C2;
        const float bC3 = bv * C3, cC4 = cv * C4;
        const float E   = bC1 + cC2;
        const float F   = bC3 + cC4;
        const float d14 = dd * C1 * C4;
        const float d23 = dd * C2 * C3;
        const float G   = av - d14;
        const float H   = av - d23;
        const float Hp2 = H * p2;
        const float D   = E * F + G * Hp2;
        const float N   = F * (bC1 - cC2) - Hp2 * (av + d14);
        const float res = N * __builtin_amdgcn_rcpf(D);

        refT[a * RT_LD + k] = (_Float16)(valid ? res : 0.0f);
    }
    // zero pad rows a = 30, 31 (column k)
    refT[30 * RT_LD + k] = (_Float16)0.0f;
    refT[31 * RT_LD + k] = (_Float16)0.0f;
    __syncthreads();

    // ---- Phase 2: MFMA GEMM (R22 chassis, verified layouts) -----------------
    // A[m=lane&15][k=quad*8+j], B[k=quad*8+j][n=lane&15], C/D[row=quad*4+r][col=n16]
    const int w    = tid >> 6;       // wave 0..3
    const int lane = tid & 63;
    const int quad = lane >> 4;      // 0..3
    const int n16  = lane & 15;

    f4 acc[4][2];
#pragma unroll
    for (int mi = 0; mi < 4; ++mi)
#pragma unroll
        for (int nt = 0; nt < 2; ++nt) acc[mi][nt] = (f4){0.f, 0.f, 0.f, 0.f};

    // Hoisted, clamped wm row pointers (R15-proven; store-masked at epilogue)
    const float* wrow[4];
#pragma unroll
    for (int mi = 0; mi < 4; ++mi) {
        const int m = (w * 4 + mi) * 16 + n16;        // logical wm row 0..255
        wrow[mi] = wm + ((m < L) ? m : (L - 1)) * L;
    }

    // ks = 0..6: cols kofs..kofs+7 <= 223 < 250 -> no clamps; 2x dwordx4
#pragma unroll
    for (int ks = 0; ks < 7; ++ks) {
        const int kofs = ks * 32 + quad * 8;
        const h8 b0  = *(const h8*)&refT[ n16       * RT_LD + kofs];
        const h8 b1v = *(const h8*)&refT[(16 + n16) * RT_LD + kofs];
#pragma unroll
        for (int mi = 0; mi < 4; ++mi) {
            const f4u g0 = *(const f4u*)(wrow[mi] + kofs);
            const f4u g1 = *(const f4u*)(wrow[mi] + kofs + 4);
            const h8 af = { (_Float16)g0[0], (_Float16)g0[1],
                            (_Float16)g0[2], (_Float16)g0[3],
                            (_Float16)g1[0], (_Float16)g1[1],
                            (_Float16)g1[2], (_Float16)g1[3] };
            acc[mi][0] = __builtin_amdgcn_mfma_f32_16x16x32_f16(af, b0,  acc[mi][0], 0, 0, 0);
            acc[mi][1] = __builtin_amdgcn_mfma_f32_16x16x32_f16(af, b1v, acc[mi][1], 0, 0, 0);
        }
    }
    { // ks = 7: cols 224..255 - only quad==3 (248..255) partial. R12 boundary
      // path verbatim: pair-clamp keeps loads in wm[0..62499], zero-select
      // keeps cols >= 250 finite (they multiply zero refT columns).
        const int kofs = 224 + quad * 8;
        const h8 b0  = *(const h8*)&refT[ n16       * RT_LD + kofs];
        const h8 b1v = *(const h8*)&refT[(16 + n16) * RT_LD + kofs];
#pragma unroll
        for (int mi = 0; mi < 4; ++mi) {
            h8 af;
#pragma unroll
            for (int c = 0; c < 4; ++c) {
                const int col  = kofs + 2 * c;                    // even
                const int colc = (col <= L - 2) ? col : (L - 2);  // pair start <= 248
                const float2 f = *(const float2*)(wrow[mi] + colc); // 8-B aligned
                af[2 * c]     = (_Float16)((col     < L) ? f.x : 0.0f);
                af[2 * c + 1] = (_Float16)((col + 1 < L) ? f.y : 0.0f);
            }
            acc[mi][0] = __builtin_amdgcn_mfma_f32_16x16x32_f16(af, b0,  acc[mi][0], 0, 0, 0);
            acc[mi][1] = __builtin_amdgcn_mfma_f32_16x16x32_f16(af, b1v, acc[mi][1], 0, 0, 0);
        }
    }

    // ---- Epilogue: D[row=quad*4+r][col=n16] -> out[t][l][a] ---- (R12 verbatim)
    float* outt = out + (size_t)t * (L * A);
#pragma unroll
    for (int mi = 0; mi < 4; ++mi) {
        const int mbase = (w * 4 + mi) * 16 + quad * 4;
#pragma unroll
        for (int nt = 0; nt < 2; ++nt) {
            const int a = nt * 16 + n16;
            if (a < A) {
#pragma unroll
                for (int r = 0; r < 4; ++r) {
                    const int l = mbase + r;
                    if (l < L) outt[l * A + a] = acc[mi][nt][r];
                }
            }
        }
    }
}

extern "C" void kernel_launch(void* const* d_in, const int* in_sizes, int n_in,
                              void* d_out, int out_size, void* d_ws, size_t ws_size,
                              hipStream_t stream) {
    (void)in_sizes; (void)n_in; (void)out_size; (void)d_ws; (void)ws_size;
    const float* vp    = (const float*)d_in[0];
    const float* vs    = (const float*)d_in[1];
    const float* rho   = (const float*)d_in[2];
    const float* theta = (const float*)d_in[3];
    const float* wm    = (const float*)d_in[4];
    float* out = (float*)d_out;

    zoep_fused<<<dim3(T), dim3(256), 0, stream>>>(vp, vs, rho, theta, wm, out);
}